// Round 4
// baseline (11417.886 us; speedup 1.0000x reference)
//
#include <hip/hip_runtime.h>
#include <hip/hip_fp16.h>
#include <cstdint>

// Problem constants
#define T_  256
#define B_  64
#define I_  1024
#define H_  1024
#define E_  4
#define C_  128
#define G4  4096   // 4*H

typedef _Float16 f16;
typedef _Float16 f16x8 __attribute__((ext_vector_type(8)));
typedef float    f32x4 __attribute__((ext_vector_type(4)));

__device__ __forceinline__ float sigmoidf_(float x) { return 1.f / (1.f + __expf(-x)); }

// ---------------- conversion f32 -> f16 (vectorized, grid-stride) -------------
__global__ void k_f32_to_f16(const float* __restrict__ src, f16* __restrict__ dst, int n8) {
    int i = blockIdx.x * blockDim.x + threadIdx.x;
    int stride = gridDim.x * blockDim.x;
    for (; i < n8; i += stride) {
        const float4* s = reinterpret_cast<const float4*>(src) + (size_t)i * 2;
        float4 a = s[0], b = s[1];
        f16x8 v = { (f16)a.x, (f16)a.y, (f16)a.z, (f16)a.w,
                    (f16)b.x, (f16)b.y, (f16)b.z, (f16)b.w };
        *reinterpret_cast<f16x8*>(dst + (size_t)i * 8) = v;
    }
}

// ---------------- mixed biases: gbias = coef@(bi+bh), bom = coef@bo ----------
__global__ void k_mix_biases(const float* __restrict__ coef, const float* __restrict__ bi,
                             const float* __restrict__ bh, const float* __restrict__ bo,
                             float* __restrict__ gbias, float* __restrict__ bom) {
    int idx = blockIdx.x * blockDim.x + threadIdx.x;
    int stride = gridDim.x * blockDim.x;
    for (int i = idx; i < B_ * G4; i += stride) {
        int b = i >> 12, o = i & (G4 - 1);
        float s = 0.f;
#pragma unroll
        for (int e = 0; e < 4; ++e) s += coef[b * 4 + e] * (bi[e * G4 + o] + bh[e * G4 + o]);
        gbias[i] = s;
    }
    for (int i = idx; i < B_ * C_; i += stride) {
        int b = i >> 7, c = i & (C_ - 1);
        float s = 0.f;
#pragma unroll
        for (int e = 0; e < 4; ++e) s += coef[b * 4 + e] * bo[e * C_ + c];
        bom[i] = s;
    }
}

// ---------------- h0 -> f16 --------------------------------------------------
__global__ void k_init_h0h(const float* __restrict__ h0, f16* __restrict__ h0h) {
    int i = blockIdx.x * blockDim.x + threadIdx.x;
    if (i < B_ * H_) h0h[i] = (f16)h0[i];
}

// ---------------- xi GEMM: per-sample mixed input projection -----------------
template<bool XF16, bool WF16>
__global__ __launch_bounds__(256, 1) void k_xi_gemm(
        const f16* __restrict__ xh, const float* __restrict__ xf,
        const f16* __restrict__ Wih, const float* __restrict__ Wif,
        const float* __restrict__ coef, const float* __restrict__ gbias,
        f16* __restrict__ xi) {
    __shared__ f16 As[256 * 72];
    __shared__ f16 Bs[128 * 72];
    const int nt = blockIdx.x;      // 0..31  (128-col tile of 4096)
    const int b  = blockIdx.y;      // 0..63
    const int tid = threadIdx.x;
    const int lane = tid & 63, wave = tid >> 6;
    const int wr = wave >> 1, wc = wave & 1;

    float cf[4];
#pragma unroll
    for (int e = 0; e < 4; ++e) cf[e] = coef[b * 4 + e];

    f32x4 acc[8][4];
#pragma unroll
    for (int mi = 0; mi < 8; ++mi)
#pragma unroll
        for (int ni = 0; ni < 4; ++ni) acc[mi][ni] = 0.f;

    for (int kk = 0; kk < I_; kk += 64) {
        __syncthreads();
#pragma unroll
        for (int it = 0; it < 8; ++it) {
            int chunk = it * 256 + tid;
            int row = chunk >> 3, c8 = chunk & 7;
            if constexpr (XF16) {
                *reinterpret_cast<f16x8*>(&As[row * 72 + c8 * 8]) =
                    *reinterpret_cast<const f16x8*>(&xh[((size_t)row * B_ + b) * I_ + kk + c8 * 8]);
            } else {
                const float4* p = reinterpret_cast<const float4*>(&xf[((size_t)row * B_ + b) * I_ + kk + c8 * 8]);
                float4 a = p[0], bq = p[1];
                f16x8 v = { (f16)a.x, (f16)a.y, (f16)a.z, (f16)a.w,
                            (f16)bq.x, (f16)bq.y, (f16)bq.z, (f16)bq.w };
                *reinterpret_cast<f16x8*>(&As[row * 72 + c8 * 8]) = v;
            }
        }
#pragma unroll
        for (int it = 0; it < 4; ++it) {
            int chunk = it * 256 + tid;
            int n = chunk >> 3, c8 = chunk & 7;
            if constexpr (WF16) {
                size_t base = ((size_t)(nt * 128 + n)) * I_ + kk + c8 * 8;
                f16 c0 = (f16)cf[0], c1 = (f16)cf[1], c2 = (f16)cf[2], c3 = (f16)cf[3];
                f16x8 w0 = *reinterpret_cast<const f16x8*>(&Wih[base]);
                f16x8 w1 = *reinterpret_cast<const f16x8*>(&Wih[base + (size_t)1 * G4 * I_]);
                f16x8 w2 = *reinterpret_cast<const f16x8*>(&Wih[base + (size_t)2 * G4 * I_]);
                f16x8 w3 = *reinterpret_cast<const f16x8*>(&Wih[base + (size_t)3 * G4 * I_]);
                f16x8 m = w0 * c0 + w1 * c1 + w2 * c2 + w3 * c3;
                *reinterpret_cast<f16x8*>(&Bs[n * 72 + c8 * 8]) = m;
            } else {
                size_t base = ((size_t)(nt * 128 + n)) * I_ + kk + c8 * 8;
                float m[8];
#pragma unroll
                for (int j = 0; j < 8; ++j) m[j] = 0.f;
#pragma unroll
                for (int e = 0; e < 4; ++e) {
                    const float4* p = reinterpret_cast<const float4*>(&Wif[base + (size_t)e * G4 * I_]);
                    float4 a = p[0], bq = p[1];
                    m[0] += cf[e] * a.x;  m[1] += cf[e] * a.y;
                    m[2] += cf[e] * a.z;  m[3] += cf[e] * a.w;
                    m[4] += cf[e] * bq.x; m[5] += cf[e] * bq.y;
                    m[6] += cf[e] * bq.z; m[7] += cf[e] * bq.w;
                }
                f16x8 v = { (f16)m[0], (f16)m[1], (f16)m[2], (f16)m[3],
                            (f16)m[4], (f16)m[5], (f16)m[6], (f16)m[7] };
                *reinterpret_cast<f16x8*>(&Bs[n * 72 + c8 * 8]) = v;
            }
        }
        __syncthreads();
#pragma unroll
        for (int ks = 0; ks < 2; ++ks) {
            int ko = ks * 32 + (lane >> 4) * 8;
            f16x8 a[8], bb[4];
#pragma unroll
            for (int mi = 0; mi < 8; ++mi)
                a[mi] = *reinterpret_cast<const f16x8*>(&As[(wr * 128 + mi * 16 + (lane & 15)) * 72 + ko]);
#pragma unroll
            for (int ni = 0; ni < 4; ++ni)
                bb[ni] = *reinterpret_cast<const f16x8*>(&Bs[(wc * 64 + ni * 16 + (lane & 15)) * 72 + ko]);
#pragma unroll
            for (int mi = 0; mi < 8; ++mi)
#pragma unroll
                for (int ni = 0; ni < 4; ++ni)
                    acc[mi][ni] = __builtin_amdgcn_mfma_f32_16x16x32_f16(a[mi], bb[ni], acc[mi][ni], 0, 0, 0);
        }
    }
#pragma unroll
    for (int mi = 0; mi < 8; ++mi)
#pragma unroll
        for (int ni = 0; ni < 4; ++ni)
#pragma unroll
            for (int j = 0; j < 4; ++j) {
                int t = wr * 128 + mi * 16 + (lane >> 4) * 4 + j;
                int o = nt * 128 + wc * 64 + ni * 16 + (lane & 15);
                float v = acc[mi][ni][j] + gbias[b * G4 + o];
                xi[((size_t)t * B_ + b) * G4 + o] = (f16)v;
            }
}

// ---------------- grid barrier (tree, fresh counters per step) ---------------
// leaf[t][jb&7] takes 32 arrivals; last arriver bumps root[t]; all spin on
// root[t]==8. ACQ_REL/ACQUIRE at AGENT scope handles cross-XCD L2 wb/inv.
__device__ __forceinline__ void grid_barrier(int* __restrict__ bar, int t, int jb) {
    __threadfence();
    __syncthreads();
    if (threadIdx.x == 0) {
        int* leaf = bar + t * 9 + (jb & 7);
        int* root = bar + t * 9 + 8;
        int prev = __hip_atomic_fetch_add(leaf, 1, __ATOMIC_ACQ_REL, __HIP_MEMORY_SCOPE_AGENT);
        if (prev == 31)
            __hip_atomic_fetch_add(root, 1, __ATOMIC_ACQ_REL, __HIP_MEMORY_SCOPE_AGENT);
        while (__hip_atomic_load(root, __ATOMIC_RELAXED, __HIP_MEMORY_SCOPE_AGENT) != 8)
            __builtin_amdgcn_s_sleep(2);
        (void)__hip_atomic_load(root, __ATOMIC_ACQUIRE, __HIP_MEMORY_SCOPE_AGENT);
    }
    __syncthreads();
}

// ---------------- persistent recurrence (cooperative, 256 blocks) ------------
// Block jb owns h-cols jb*4..+4. Its 131KB Whh slice (64 rows x K=1024) lives
// in REGISTERS (32 x f16x8 per thread, native MFMA B-frag layout) for all 256
// steps. c-state lives in a register. Per step: stage h_prev into a
// double-buffered LDS A-tile, 128 MFMA, LDS expert-mix, cell update, write h
// into xi[t] gate-0 (overlay), tree grid-barrier.
__global__ __launch_bounds__(256, 1) void k_rec_persist(
        const f16* __restrict__ Whh, const f16* __restrict__ h0h,
        const float* __restrict__ c0, f16* xi, const float* __restrict__ coef,
        float* __restrict__ out, int* __restrict__ bar) {
    __shared__ f16 As[2][64 * 72];
    __shared__ float gl[4][64][17];
    const int jb = blockIdx.x;
    const int tid = threadIdx.x, lane = tid & 63, w = tid >> 6;   // wave = expert

    // cell-update identity (fixed across steps)
    const int bb = tid >> 2, cl = tid & 3;
    const int col = jb * 4 + cl;
    float c_reg = c0[bb * H_ + col];
    const float4 cf4 = *reinterpret_cast<const float4*>(&coef[bb * 4]);

    // register-resident Wh B-fragments: n=lane&15 -> (gate,col); 32 K-chunks
    const int n = lane & 15;
    const size_t grow = (size_t)w * G4 + (size_t)(n >> 2) * H_ + jb * 4 + (n & 3);
    const f16* wp = Whh + grow * H_ + (lane >> 4) * 8;
    f16x8 breg[32];
#pragma unroll
    for (int k = 0; k < 32; ++k)
        breg[k] = *reinterpret_cast<const f16x8*>(wp + (size_t)k * 32);

    // A-staging identity: rows tid>>3 and 32+(tid>>3), col-octet tid&7
    const int sr = tid >> 3, s8 = (tid & 7) * 8;

    for (int t = 0; t < T_; ++t) {
        const f16* hprev = (t == 0) ? h0h : (xi + (size_t)(t - 1) * B_ * G4);
        const size_t hstr = (t == 0) ? (size_t)H_ : (size_t)G4;

        // early xi gate loads (consumed in epilogue; latency hides under K-loop)
        float xg[4];
#pragma unroll
        for (int g = 0; g < 4; ++g)
            xg[g] = (float)xi[((size_t)t * B_ + bb) * G4 + g * H_ + col];

        // prologue: stage K-tile 0
        {
            f16x8 v0 = *reinterpret_cast<const f16x8*>(&hprev[(size_t)sr * hstr + s8]);
            f16x8 v1 = *reinterpret_cast<const f16x8*>(&hprev[(size_t)(32 + sr) * hstr + s8]);
            *reinterpret_cast<f16x8*>(&As[0][sr * 72 + s8]) = v0;
            *reinterpret_cast<f16x8*>(&As[0][(32 + sr) * 72 + s8]) = v1;
        }
        f32x4 acc[4];
#pragma unroll
        for (int mi = 0; mi < 4; ++mi) acc[mi] = 0.f;
        __syncthreads();

#pragma unroll
        for (int kk = 0; kk < 16; ++kk) {
            f16x8 p0, p1;
            if (kk < 15) {   // prefetch next K-tile (uniform branch)
                int kc = (kk + 1) * 64;
                p0 = *reinterpret_cast<const f16x8*>(&hprev[(size_t)sr * hstr + kc + s8]);
                p1 = *reinterpret_cast<const f16x8*>(&hprev[(size_t)(32 + sr) * hstr + kc + s8]);
            }
            const f16* Ab = As[kk & 1];
#pragma unroll
            for (int ks = 0; ks < 2; ++ks) {
                int ko = ks * 32 + (lane >> 4) * 8;
#pragma unroll
                for (int mi = 0; mi < 4; ++mi) {
                    f16x8 a = *reinterpret_cast<const f16x8*>(&Ab[(mi * 16 + (lane & 15)) * 72 + ko]);
                    acc[mi] = __builtin_amdgcn_mfma_f32_16x16x32_f16(a, breg[kk * 2 + ks], acc[mi], 0, 0, 0);
                }
            }
            if (kk < 15) {
                f16* Aw = As[(kk + 1) & 1];
                *reinterpret_cast<f16x8*>(&Aw[sr * 72 + s8]) = p0;
                *reinterpret_cast<f16x8*>(&Aw[(32 + sr) * 72 + s8]) = p1;
            }
            __syncthreads();
        }

        // park per-expert partials
#pragma unroll
        for (int mi = 0; mi < 4; ++mi)
#pragma unroll
            for (int j = 0; j < 4; ++j)
                gl[w][mi * 16 + (lane >> 4) * 4 + j][lane & 15] = acc[mi][j];
        __syncthreads();

        // mix experts + cell update (thread -> (bb, col))
        float gate[4];
#pragma unroll
        for (int g = 0; g < 4; ++g) {
            int nn = g * 4 + cl;
            gate[g] = cf4.x * gl[0][bb][nn] + cf4.y * gl[1][bb][nn] +
                      cf4.z * gl[2][bb][nn] + cf4.w * gl[3][bb][nn] + xg[g];
        }
        float cn = sigmoidf_(gate[1]) * c_reg + sigmoidf_(gate[0]) * tanhf(gate[2]);
        float hn = sigmoidf_(gate[3]) * tanhf(cn);
        c_reg = cn;
        xi[((size_t)t * B_ + bb) * G4 + col] = (f16)hn;   // h[t] overlay (gate-0)
        if (t == T_ - 1) {
            out[(size_t)T_ * B_ * C_ + bb * H_ + col] = hn;
            out[(size_t)T_ * B_ * C_ + B_ * H_ + bb * H_ + col] = cn;
        } else {
            grid_barrier(bar, t, jb);
        }
    }
}

// ---------------- output projection ------------------------------------------
__global__ __launch_bounds__(256, 1) void k_out_gemm(
        const f16* __restrict__ hs, const f16* __restrict__ Woh,
        const float* __restrict__ coef, const float* __restrict__ bom,
        float* __restrict__ out) {
    __shared__ f16 As[64 * 72];
    __shared__ f16 Bs[256 * 72];
    __shared__ float cfs[64][4];
    const int nt = blockIdx.x;   // 0..1
    const int t  = blockIdx.y;   // 0..255
    const int tid = threadIdx.x, lane = tid & 63, w = tid >> 6;
    cfs[tid >> 2][tid & 3] = coef[tid];

    f32x4 acc[4][4];
#pragma unroll
    for (int e = 0; e < 4; ++e)
#pragma unroll
        for (int mi = 0; mi < 4; ++mi) acc[e][mi] = 0.f;

    for (int kk = 0; kk < H_; kk += 64) {
        __syncthreads();
#pragma unroll
        for (int it = 0; it < 2; ++it) {   // A: hs[t] 64x64 (stride G4 overlay)
            int chunk = it * 256 + tid;
            int row = chunk >> 3, c8 = chunk & 7;
            *reinterpret_cast<f16x8*>(&As[row * 72 + c8 * 8]) =
                *reinterpret_cast<const f16x8*>(&hs[((size_t)t * B_ + row) * G4 + kk + c8 * 8]);
        }
#pragma unroll
        for (int it = 0; it < 8; ++it) {   // B: Wo rows e*C + nt*64 + n
            int chunk = it * 256 + tid;
            int r = chunk >> 3, c8 = chunk & 7;
            int e = r >> 6, nn = r & 63;
            size_t grow = (size_t)e * C_ + nt * 64 + nn;
            *reinterpret_cast<f16x8*>(&Bs[r * 72 + c8 * 8]) =
                *reinterpret_cast<const f16x8*>(&Woh[grow * H_ + kk + c8 * 8]);
        }
        __syncthreads();
#pragma unroll
        for (int ks = 0; ks < 2; ++ks) {
            int ko = ks * 32 + (lane >> 4) * 8;
            f16x8 a[4];
#pragma unroll
            for (int mi = 0; mi < 4; ++mi)
                a[mi] = *reinterpret_cast<const f16x8*>(&As[(mi * 16 + (lane & 15)) * 72 + ko]);
#pragma unroll
            for (int e = 0; e < 4; ++e) {
                f16x8 bf = *reinterpret_cast<const f16x8*>(&Bs[(e * 64 + w * 16 + (lane & 15)) * 72 + ko]);
#pragma unroll
                for (int mi = 0; mi < 4; ++mi)
                    acc[e][mi] = __builtin_amdgcn_mfma_f32_16x16x32_f16(a[mi], bf, acc[e][mi], 0, 0, 0);
            }
        }
    }
#pragma unroll
    for (int mi = 0; mi < 4; ++mi)
#pragma unroll
        for (int j = 0; j < 4; ++j) {
            int bb = mi * 16 + (lane >> 4) * 4 + j;
            int cc = nt * 64 + w * 16 + (lane & 15);
            float v = cfs[bb][0] * acc[0][mi][j] + cfs[bb][1] * acc[1][mi][j] +
                      cfs[bb][2] * acc[2][mi][j] + cfs[bb][3] * acc[3][mi][j];
            v += bom[bb * C_ + cc];
            out[((size_t)t * B_ + bb) * C_ + cc] = v;
        }
}

extern "C" void kernel_launch(void* const* d_in, const int* in_sizes, int n_in,
                              void* d_out, int out_size, void* d_ws, size_t ws_size,
                              hipStream_t stream) {
    const float* x    = (const float*)d_in[0];
    const float* h0   = (const float*)d_in[1];
    const float* c0   = (const float*)d_in[2];
    const float* coef = (const float*)d_in[3];
    const float* Wi   = (const float*)d_in[4];
    const float* bi   = (const float*)d_in[5];
    const float* Wh   = (const float*)d_in[6];
    const float* bh   = (const float*)d_in[7];
    const float* Wo   = (const float*)d_in[8];
    const float* bo   = (const float*)d_in[9];
    float* out = (float*)d_out;

    char* base = (char*)d_ws;
    size_t off = 0;
    auto carve = [&](size_t bytes) -> char* {
        char* r = base + off;
        off = (off + bytes + 255) & ~(size_t)255;
        return r;
    };
    const size_t SZ_XI  = (size_t)T_ * B_ * G4 * 2;   // 134.2 MB (gate-0 doubles as hs)
    const size_t SZ_WHH = (size_t)E_ * G4 * H_ * 2;   // 33.5 MB
    const size_t SZ_WOH = (size_t)E_ * C_ * H_ * 2;   // 1 MB
    const size_t SZ_BAR = (size_t)T_ * 9 * 4;         // barrier counters
    const size_t SZ_WIH = (size_t)E_ * G4 * I_ * 2;   // 33.5 MB (optional)
    const size_t SZ_XH  = (size_t)T_ * B_ * I_ * 2;   // 33.5 MB (optional)

    f16*   xi     = (f16*)carve(SZ_XI);
    f16*   Whh    = (f16*)carve(SZ_WHH);
    f16*   Woh    = (f16*)carve(SZ_WOH);
    f16*   h0h    = (f16*)carve((size_t)B_ * H_ * 2);
    float* gbias  = (float*)carve((size_t)B_ * G4 * 4);
    float* bom    = (float*)carve((size_t)B_ * C_ * 4);
    int*   bar    = (int*)carve(SZ_BAR);

    f16* Wih = nullptr;
    f16* xh  = nullptr;
    if (off + SZ_WIH + 256 <= ws_size) Wih = (f16*)carve(SZ_WIH);
    if (Wih && off + SZ_XH + 256 <= ws_size) xh = (f16*)carve(SZ_XH);
    (void)in_sizes; (void)n_in; (void)out_size;

    hipMemsetAsync(bar, 0, SZ_BAR, stream);

    if (xh)  k_f32_to_f16<<<2048, 256, 0, stream>>>(x,  xh,  (T_ * B_ * I_) / 8);
    if (Wih) k_f32_to_f16<<<2048, 256, 0, stream>>>(Wi, Wih, (E_ * G4 * I_) / 8);
    k_f32_to_f16<<<2048, 256, 0, stream>>>(Wh, Whh, (E_ * G4 * H_) / 8);
    k_f32_to_f16<<<512,  256, 0, stream>>>(Wo, Woh, (E_ * C_ * H_) / 8);
    k_mix_biases<<<512, 256, 0, stream>>>(coef, bi, bh, bo, gbias, bom);
    k_init_h0h<<<(B_ * H_ + 255) / 256, 256, 0, stream>>>(h0, h0h);

    dim3 gx(32, 64);
    if (xh)
        k_xi_gemm<true,  true ><<<gx, 256, 0, stream>>>(xh, nullptr, Wih, nullptr, coef, gbias, xi);
    else if (Wih)
        k_xi_gemm<false, true ><<<gx, 256, 0, stream>>>(nullptr, x, Wih, nullptr, coef, gbias, xi);
    else
        k_xi_gemm<false, false><<<gx, 256, 0, stream>>>(nullptr, x, nullptr, Wi, coef, gbias, xi);

    // persistent recurrence: one cooperative launch, 256 blocks = 1/CU
    {
        void* args[] = { (void*)&Whh, (void*)&h0h, (void*)&c0, (void*)&xi,
                         (void*)&coef, (void*)&out, (void*)&bar };
        hipLaunchCooperativeKernel((const void*)k_rec_persist, dim3(256), dim3(256),
                                   args, 0, stream);
    }

    dim3 go(2, 256);
    k_out_gemm<<<go, 256, 0, stream>>>(xi, Woh, coef, bom, out);
}

// Round 5
// 11175.001 us; speedup vs baseline: 1.0217x; 1.0217x over previous
//
#include <hip/hip_runtime.h>
#include <hip/hip_fp16.h>
#include <cstdint>

// Problem constants
#define T_  256
#define B_  64
#define I_  1024
#define H_  1024
#define E_  4
#define C_  128
#define G4  4096   // 4*H

typedef _Float16 f16;
typedef _Float16 f16x8 __attribute__((ext_vector_type(8)));
typedef float    f32x4 __attribute__((ext_vector_type(4)));

__device__ __forceinline__ float sigmoidf_(float x) { return 1.f / (1.f + __expf(-x)); }

// ---------------- conversion f32 -> f16 (vectorized, grid-stride) -------------
__global__ void k_f32_to_f16(const float* __restrict__ src, f16* __restrict__ dst, int n8) {
    int i = blockIdx.x * blockDim.x + threadIdx.x;
    int stride = gridDim.x * blockDim.x;
    for (; i < n8; i += stride) {
        const float4* s = reinterpret_cast<const float4*>(src) + (size_t)i * 2;
        float4 a = s[0], b = s[1];
        f16x8 v = { (f16)a.x, (f16)a.y, (f16)a.z, (f16)a.w,
                    (f16)b.x, (f16)b.y, (f16)b.z, (f16)b.w };
        *reinterpret_cast<f16x8*>(dst + (size_t)i * 8) = v;
    }
}

// ---------------- mixed biases: gbias = coef@(bi+bh), bom = coef@bo ----------
__global__ void k_mix_biases(const float* __restrict__ coef, const float* __restrict__ bi,
                             const float* __restrict__ bh, const float* __restrict__ bo,
                             float* __restrict__ gbias, float* __restrict__ bom) {
    int idx = blockIdx.x * blockDim.x + threadIdx.x;
    int stride = gridDim.x * blockDim.x;
    for (int i = idx; i < B_ * G4; i += stride) {
        int b = i >> 12, o = i & (G4 - 1);
        float s = 0.f;
#pragma unroll
        for (int e = 0; e < 4; ++e) s += coef[b * 4 + e] * (bi[e * G4 + o] + bh[e * G4 + o]);
        gbias[i] = s;
    }
    for (int i = idx; i < B_ * C_; i += stride) {
        int b = i >> 7, c = i & (C_ - 1);
        float s = 0.f;
#pragma unroll
        for (int e = 0; e < 4; ++e) s += coef[b * 4 + e] * bo[e * C_ + c];
        bom[i] = s;
    }
}

// ---------------- h0 -> f16 --------------------------------------------------
__global__ void k_init_h0h(const float* __restrict__ h0, f16* __restrict__ h0h) {
    int i = blockIdx.x * blockDim.x + threadIdx.x;
    if (i < B_ * H_) h0h[i] = (f16)h0[i];
}

// ---------------- xi GEMM: per-sample mixed input projection -----------------
template<bool XF16, bool WF16>
__global__ __launch_bounds__(256, 1) void k_xi_gemm(
        const f16* __restrict__ xh, const float* __restrict__ xf,
        const f16* __restrict__ Wih, const float* __restrict__ Wif,
        const float* __restrict__ coef, const float* __restrict__ gbias,
        f16* __restrict__ xi) {
    __shared__ f16 As[256 * 72];
    __shared__ f16 Bs[128 * 72];
    const int nt = blockIdx.x;      // 0..31  (128-col tile of 4096)
    const int b  = blockIdx.y;      // 0..63
    const int tid = threadIdx.x;
    const int lane = tid & 63, wave = tid >> 6;
    const int wr = wave >> 1, wc = wave & 1;

    float cf[4];
#pragma unroll
    for (int e = 0; e < 4; ++e) cf[e] = coef[b * 4 + e];

    f32x4 acc[8][4];
#pragma unroll
    for (int mi = 0; mi < 8; ++mi)
#pragma unroll
        for (int ni = 0; ni < 4; ++ni) acc[mi][ni] = 0.f;

    for (int kk = 0; kk < I_; kk += 64) {
        __syncthreads();
#pragma unroll
        for (int it = 0; it < 8; ++it) {
            int chunk = it * 256 + tid;
            int row = chunk >> 3, c8 = chunk & 7;
            if constexpr (XF16) {
                *reinterpret_cast<f16x8*>(&As[row * 72 + c8 * 8]) =
                    *reinterpret_cast<const f16x8*>(&xh[((size_t)row * B_ + b) * I_ + kk + c8 * 8]);
            } else {
                const float4* p = reinterpret_cast<const float4*>(&xf[((size_t)row * B_ + b) * I_ + kk + c8 * 8]);
                float4 a = p[0], bq = p[1];
                f16x8 v = { (f16)a.x, (f16)a.y, (f16)a.z, (f16)a.w,
                            (f16)bq.x, (f16)bq.y, (f16)bq.z, (f16)bq.w };
                *reinterpret_cast<f16x8*>(&As[row * 72 + c8 * 8]) = v;
            }
        }
#pragma unroll
        for (int it = 0; it < 4; ++it) {
            int chunk = it * 256 + tid;
            int n = chunk >> 3, c8 = chunk & 7;
            if constexpr (WF16) {
                size_t base = ((size_t)(nt * 128 + n)) * I_ + kk + c8 * 8;
                f16 c0 = (f16)cf[0], c1 = (f16)cf[1], c2 = (f16)cf[2], c3 = (f16)cf[3];
                f16x8 w0 = *reinterpret_cast<const f16x8*>(&Wih[base]);
                f16x8 w1 = *reinterpret_cast<const f16x8*>(&Wih[base + (size_t)1 * G4 * I_]);
                f16x8 w2 = *reinterpret_cast<const f16x8*>(&Wih[base + (size_t)2 * G4 * I_]);
                f16x8 w3 = *reinterpret_cast<const f16x8*>(&Wih[base + (size_t)3 * G4 * I_]);
                f16x8 m = w0 * c0 + w1 * c1 + w2 * c2 + w3 * c3;
                *reinterpret_cast<f16x8*>(&Bs[n * 72 + c8 * 8]) = m;
            } else {
                size_t base = ((size_t)(nt * 128 + n)) * I_ + kk + c8 * 8;
                float m[8];
#pragma unroll
                for (int j = 0; j < 8; ++j) m[j] = 0.f;
#pragma unroll
                for (int e = 0; e < 4; ++e) {
                    const float4* p = reinterpret_cast<const float4*>(&Wif[base + (size_t)e * G4 * I_]);
                    float4 a = p[0], bq = p[1];
                    m[0] += cf[e] * a.x;  m[1] += cf[e] * a.y;
                    m[2] += cf[e] * a.z;  m[3] += cf[e] * a.w;
                    m[4] += cf[e] * bq.x; m[5] += cf[e] * bq.y;
                    m[6] += cf[e] * bq.z; m[7] += cf[e] * bq.w;
                }
                f16x8 v = { (f16)m[0], (f16)m[1], (f16)m[2], (f16)m[3],
                            (f16)m[4], (f16)m[5], (f16)m[6], (f16)m[7] };
                *reinterpret_cast<f16x8*>(&Bs[n * 72 + c8 * 8]) = v;
            }
        }
        __syncthreads();
#pragma unroll
        for (int ks = 0; ks < 2; ++ks) {
            int ko = ks * 32 + (lane >> 4) * 8;
            f16x8 a[8], bb[4];
#pragma unroll
            for (int mi = 0; mi < 8; ++mi)
                a[mi] = *reinterpret_cast<const f16x8*>(&As[(wr * 128 + mi * 16 + (lane & 15)) * 72 + ko]);
#pragma unroll
            for (int ni = 0; ni < 4; ++ni)
                bb[ni] = *reinterpret_cast<const f16x8*>(&Bs[(wc * 64 + ni * 16 + (lane & 15)) * 72 + ko]);
#pragma unroll
            for (int mi = 0; mi < 8; ++mi)
#pragma unroll
                for (int ni = 0; ni < 4; ++ni)
                    acc[mi][ni] = __builtin_amdgcn_mfma_f32_16x16x32_f16(a[mi], bb[ni], acc[mi][ni], 0, 0, 0);
        }
    }
#pragma unroll
    for (int mi = 0; mi < 8; ++mi)
#pragma unroll
        for (int ni = 0; ni < 4; ++ni)
#pragma unroll
            for (int j = 0; j < 4; ++j) {
                int t = wr * 128 + mi * 16 + (lane >> 4) * 4 + j;
                int o = nt * 128 + wc * 64 + ni * 16 + (lane & 15);
                float v = acc[mi][ni][j] + gbias[b * G4 + o];
                xi[((size_t)t * B_ + b) * G4 + o] = (f16)v;
            }
}

// ---------------- grid barrier (tree, fresh counters per step) ---------------
__device__ __forceinline__ void grid_barrier(int* __restrict__ bar, int t, int jb) {
    __threadfence();
    __syncthreads();
    if (threadIdx.x == 0) {
        int* leaf = bar + t * 9 + (jb & 7);
        int* root = bar + t * 9 + 8;
        int prev = __hip_atomic_fetch_add(leaf, 1, __ATOMIC_ACQ_REL, __HIP_MEMORY_SCOPE_AGENT);
        if (prev == 31)
            __hip_atomic_fetch_add(root, 1, __ATOMIC_ACQ_REL, __HIP_MEMORY_SCOPE_AGENT);
        while (__hip_atomic_load(root, __ATOMIC_RELAXED, __HIP_MEMORY_SCOPE_AGENT) != 8)
            __builtin_amdgcn_s_sleep(2);
        (void)__hip_atomic_load(root, __ATOMIC_ACQUIRE, __HIP_MEMORY_SCOPE_AGENT);
    }
    __syncthreads();
}

// ---------------- persistent recurrence (cooperative, 256 blocks) ------------
// Block jb owns h-cols jb*4..+4. Its 131KB Whh slice lives in 32 NAMED f16x8
// registers per thread (hand-unrolled K-loop -> every reference is a distinct
// named register; rule-#20-proof, no scratch). c-state in a register.
// Per step: double-buffered LDS A-tile of h_prev, 128 MFMA/wave, LDS expert
// mix, cell update, h[t] -> xi[t] gate-0 overlay, tree grid-barrier.

#define AL(ABUF, MI, KOFF) \
    (*reinterpret_cast<const f16x8*>(&ABUF[((MI) * 16 + l15) * 72 + (KOFF) + hi8]))

#define MMPAIR(ABUF, BW0, BW1) \
    acc0 = __builtin_amdgcn_mfma_f32_16x16x32_f16(AL(ABUF, 0, 0),  BW0, acc0, 0, 0, 0); \
    acc1 = __builtin_amdgcn_mfma_f32_16x16x32_f16(AL(ABUF, 1, 0),  BW0, acc1, 0, 0, 0); \
    acc2 = __builtin_amdgcn_mfma_f32_16x16x32_f16(AL(ABUF, 2, 0),  BW0, acc2, 0, 0, 0); \
    acc3 = __builtin_amdgcn_mfma_f32_16x16x32_f16(AL(ABUF, 3, 0),  BW0, acc3, 0, 0, 0); \
    acc0 = __builtin_amdgcn_mfma_f32_16x16x32_f16(AL(ABUF, 0, 32), BW1, acc0, 0, 0, 0); \
    acc1 = __builtin_amdgcn_mfma_f32_16x16x32_f16(AL(ABUF, 1, 32), BW1, acc1, 0, 0, 0); \
    acc2 = __builtin_amdgcn_mfma_f32_16x16x32_f16(AL(ABUF, 2, 32), BW1, acc2, 0, 0, 0); \
    acc3 = __builtin_amdgcn_mfma_f32_16x16x32_f16(AL(ABUF, 3, 32), BW1, acc3, 0, 0, 0);

// full K-step: prefetch tile KK+1, MFMA on tile KK, write tile KK+1, sync
#define KSTEP(KK, AB, AW, BW0, BW1) { \
    const f16x8 p0 = *reinterpret_cast<const f16x8*>(&hprev[(size_t)sr * hstr + ((KK) + 1) * 64 + s8]); \
    const f16x8 p1 = *reinterpret_cast<const f16x8*>(&hprev[(size_t)(32 + sr) * hstr + ((KK) + 1) * 64 + s8]); \
    MMPAIR(AB, BW0, BW1); \
    *reinterpret_cast<f16x8*>(&AW[sr * 72 + s8]) = p0; \
    *reinterpret_cast<f16x8*>(&AW[(32 + sr) * 72 + s8]) = p1; \
    __syncthreads(); \
}

__global__ __launch_bounds__(256, 1) void k_rec_persist(
        const f16* __restrict__ Whh, const f16* __restrict__ h0h,
        const float* __restrict__ c0, f16* xi, const float* __restrict__ coef,
        float* __restrict__ out, int* __restrict__ bar) {
    __shared__ f16 As0[64 * 72];
    __shared__ f16 As1[64 * 72];
    __shared__ float gl[4][64][17];
    const int jb = blockIdx.x;
    const int tid = threadIdx.x, lane = tid & 63, w = tid >> 6;   // wave = expert
    const int l15 = lane & 15, hi8 = (lane >> 4) * 8;

    // cell-update identity (fixed across steps)
    const int bb = tid >> 2, cl = tid & 3;
    const int col = jb * 4 + cl;
    float c_reg = c0[bb * H_ + col];
    const float4 cf4 = *reinterpret_cast<const float4*>(&coef[bb * 4]);

    // Wh B-fragments in 32 NAMED registers: n=l15 -> (gate,col); K-chunk k
    // covers h-cols k*32 + hi8 + 0..7
    const size_t grow = (size_t)w * G4 + (size_t)(l15 >> 2) * H_ + jb * 4 + (l15 & 3);
    const f16* wp = Whh + grow * H_ + hi8;
#define LOADW(K) const f16x8 bw##K = *reinterpret_cast<const f16x8*>(wp + (size_t)(K) * 32);
    LOADW(0)  LOADW(1)  LOADW(2)  LOADW(3)  LOADW(4)  LOADW(5)  LOADW(6)  LOADW(7)
    LOADW(8)  LOADW(9)  LOADW(10) LOADW(11) LOADW(12) LOADW(13) LOADW(14) LOADW(15)
    LOADW(16) LOADW(17) LOADW(18) LOADW(19) LOADW(20) LOADW(21) LOADW(22) LOADW(23)
    LOADW(24) LOADW(25) LOADW(26) LOADW(27) LOADW(28) LOADW(29) LOADW(30) LOADW(31)
#undef LOADW

    // A-staging identity: rows tid>>3 and 32+(tid>>3), col-octet tid&7
    const int sr = tid >> 3, s8 = (tid & 7) * 8;

    for (int t = 0; t < T_; ++t) {
        const f16* hprev = (t == 0) ? h0h : (xi + (size_t)(t - 1) * B_ * G4);
        const size_t hstr = (t == 0) ? (size_t)H_ : (size_t)G4;

        // early xi gate loads (consumed in epilogue; latency hides under K-loop)
        float xg0 = (float)xi[((size_t)t * B_ + bb) * G4 + 0 * H_ + col];
        float xg1 = (float)xi[((size_t)t * B_ + bb) * G4 + 1 * H_ + col];
        float xg2 = (float)xi[((size_t)t * B_ + bb) * G4 + 2 * H_ + col];
        float xg3 = (float)xi[((size_t)t * B_ + bb) * G4 + 3 * H_ + col];

        // prologue: stage K-tile 0 into As0
        {
            f16x8 v0 = *reinterpret_cast<const f16x8*>(&hprev[(size_t)sr * hstr + s8]);
            f16x8 v1 = *reinterpret_cast<const f16x8*>(&hprev[(size_t)(32 + sr) * hstr + s8]);
            *reinterpret_cast<f16x8*>(&As0[sr * 72 + s8]) = v0;
            *reinterpret_cast<f16x8*>(&As0[(32 + sr) * 72 + s8]) = v1;
        }
        f32x4 acc0 = {0.f, 0.f, 0.f, 0.f}, acc1 = {0.f, 0.f, 0.f, 0.f};
        f32x4 acc2 = {0.f, 0.f, 0.f, 0.f}, acc3 = {0.f, 0.f, 0.f, 0.f};
        __syncthreads();

        KSTEP(0,  As0, As1, bw0,  bw1)
        KSTEP(1,  As1, As0, bw2,  bw3)
        KSTEP(2,  As0, As1, bw4,  bw5)
        KSTEP(3,  As1, As0, bw6,  bw7)
        KSTEP(4,  As0, As1, bw8,  bw9)
        KSTEP(5,  As1, As0, bw10, bw11)
        KSTEP(6,  As0, As1, bw12, bw13)
        KSTEP(7,  As1, As0, bw14, bw15)
        KSTEP(8,  As0, As1, bw16, bw17)
        KSTEP(9,  As1, As0, bw18, bw19)
        KSTEP(10, As0, As1, bw20, bw21)
        KSTEP(11, As1, As0, bw22, bw23)
        KSTEP(12, As0, As1, bw24, bw25)
        KSTEP(13, As1, As0, bw26, bw27)
        KSTEP(14, As0, As1, bw28, bw29)
        // last K-step: no prefetch
        MMPAIR(As1, bw30, bw31)

        // park per-expert partials (acc row r = mi*16 + (lane>>4)*4 + j)
#pragma unroll
        for (int j = 0; j < 4; ++j) {
            gl[w][0 * 16 + (lane >> 4) * 4 + j][l15] = acc0[j];
            gl[w][1 * 16 + (lane >> 4) * 4 + j][l15] = acc1[j];
            gl[w][2 * 16 + (lane >> 4) * 4 + j][l15] = acc2[j];
            gl[w][3 * 16 + (lane >> 4) * 4 + j][l15] = acc3[j];
        }
        __syncthreads();

        // mix experts + cell update (thread -> (bb, col))
        float gate[4];
#pragma unroll
        for (int g = 0; g < 4; ++g) {
            int nn = g * 4 + cl;
            gate[g] = cf4.x * gl[0][bb][nn] + cf4.y * gl[1][bb][nn] +
                      cf4.z * gl[2][bb][nn] + cf4.w * gl[3][bb][nn];
        }
        gate[0] += xg0; gate[1] += xg1; gate[2] += xg2; gate[3] += xg3;
        float cn = sigmoidf_(gate[1]) * c_reg + sigmoidf_(gate[0]) * tanhf(gate[2]);
        float hn = sigmoidf_(gate[3]) * tanhf(cn);
        c_reg = cn;
        xi[((size_t)t * B_ + bb) * G4 + col] = (f16)hn;   // h[t] overlay (gate-0)
        if (t == T_ - 1) {
            out[(size_t)T_ * B_ * C_ + bb * H_ + col] = hn;
            out[(size_t)T_ * B_ * C_ + B_ * H_ + bb * H_ + col] = cn;
        } else {
            grid_barrier(bar, t, jb);
        }
    }
}

// ---------------- output projection ------------------------------------------
__global__ __launch_bounds__(256, 1) void k_out_gemm(
        const f16* __restrict__ hs, const f16* __restrict__ Woh,
        const float* __restrict__ coef, const float* __restrict__ bom,
        float* __restrict__ out) {
    __shared__ f16 As[64 * 72];
    __shared__ f16 Bs[256 * 72];
    __shared__ float cfs[64][4];
    const int nt = blockIdx.x;   // 0..1
    const int t  = blockIdx.y;   // 0..255
    const int tid = threadIdx.x, lane = tid & 63, w = tid >> 6;
    cfs[tid >> 2][tid & 3] = coef[tid];

    f32x4 acc[4][4];
#pragma unroll
    for (int e = 0; e < 4; ++e)
#pragma unroll
        for (int mi = 0; mi < 4; ++mi) acc[e][mi] = 0.f;

    for (int kk = 0; kk < H_; kk += 64) {
        __syncthreads();
#pragma unroll
        for (int it = 0; it < 2; ++it) {   // A: hs[t] 64x64 (stride G4 overlay)
            int chunk = it * 256 + tid;
            int row = chunk >> 3, c8 = chunk & 7;
            *reinterpret_cast<f16x8*>(&As[row * 72 + c8 * 8]) =
                *reinterpret_cast<const f16x8*>(&hs[((size_t)t * B_ + row) * G4 + kk + c8 * 8]);
        }
#pragma unroll
        for (int it = 0; it < 8; ++it) {   // B: Wo rows e*C + nt*64 + n
            int chunk = it * 256 + tid;
            int r = chunk >> 3, c8 = chunk & 7;
            int e = r >> 6, nn = r & 63;
            size_t grow = (size_t)e * C_ + nt * 64 + nn;
            *reinterpret_cast<f16x8*>(&Bs[r * 72 + c8 * 8]) =
                *reinterpret_cast<const f16x8*>(&Woh[grow * H_ + kk + c8 * 8]);
        }
        __syncthreads();
#pragma unroll
        for (int ks = 0; ks < 2; ++ks) {
            int ko = ks * 32 + (lane >> 4) * 8;
            f16x8 a[4];
#pragma unroll
            for (int mi = 0; mi < 4; ++mi)
                a[mi] = *reinterpret_cast<const f16x8*>(&As[(mi * 16 + (lane & 15)) * 72 + ko]);
#pragma unroll
            for (int e = 0; e < 4; ++e) {
                f16x8 bf = *reinterpret_cast<const f16x8*>(&Bs[(e * 64 + w * 16 + (lane & 15)) * 72 + ko]);
#pragma unroll
                for (int mi = 0; mi < 4; ++mi)
                    acc[e][mi] = __builtin_amdgcn_mfma_f32_16x16x32_f16(a[mi], bf, acc[e][mi], 0, 0, 0);
            }
        }
    }
#pragma unroll
    for (int mi = 0; mi < 4; ++mi)
#pragma unroll
        for (int j = 0; j < 4; ++j) {
            int bb = mi * 16 + (lane >> 4) * 4 + j;
            int cc = nt * 64 + w * 16 + (lane & 15);
            float v = cfs[bb][0] * acc[0][mi][j] + cfs[bb][1] * acc[1][mi][j] +
                      cfs[bb][2] * acc[2][mi][j] + cfs[bb][3] * acc[3][mi][j];
            v += bom[bb * C_ + cc];
            out[((size_t)t * B_ + bb) * C_ + cc] = v;
        }
}

extern "C" void kernel_launch(void* const* d_in, const int* in_sizes, int n_in,
                              void* d_out, int out_size, void* d_ws, size_t ws_size,
                              hipStream_t stream) {
    const float* x    = (const float*)d_in[0];
    const float* h0   = (const float*)d_in[1];
    const float* c0   = (const float*)d_in[2];
    const float* coef = (const float*)d_in[3];
    const float* Wi   = (const float*)d_in[4];
    const float* bi   = (const float*)d_in[5];
    const float* Wh   = (const float*)d_in[6];
    const float* bh   = (const float*)d_in[7];
    const float* Wo   = (const float*)d_in[8];
    const float* bo   = (const float*)d_in[9];
    float* out = (float*)d_out;

    char* base = (char*)d_ws;
    size_t off = 0;
    auto carve = [&](size_t bytes) -> char* {
        char* r = base + off;
        off = (off + bytes + 255) & ~(size_t)255;
        return r;
    };
    const size_t SZ_XI  = (size_t)T_ * B_ * G4 * 2;   // 134.2 MB (gate-0 doubles as hs)
    const size_t SZ_WHH = (size_t)E_ * G4 * H_ * 2;   // 33.5 MB
    const size_t SZ_WOH = (size_t)E_ * C_ * H_ * 2;   // 1 MB
    const size_t SZ_BAR = (size_t)T_ * 9 * 4;         // barrier counters
    const size_t SZ_WIH = (size_t)E_ * G4 * I_ * 2;   // 33.5 MB (optional)
    const size_t SZ_XH  = (size_t)T_ * B_ * I_ * 2;   // 33.5 MB (optional)

    f16*   xi     = (f16*)carve(SZ_XI);
    f16*   Whh    = (f16*)carve(SZ_WHH);
    f16*   Woh    = (f16*)carve(SZ_WOH);
    f16*   h0h    = (f16*)carve((size_t)B_ * H_ * 2);
    float* gbias  = (float*)carve((size_t)B_ * G4 * 4);
    float* bom    = (float*)carve((size_t)B_ * C_ * 4);
    int*   bar    = (int*)carve(SZ_BAR);

    f16* Wih = nullptr;
    f16* xh  = nullptr;
    if (off + SZ_WIH + 256 <= ws_size) Wih = (f16*)carve(SZ_WIH);
    if (Wih && off + SZ_XH + 256 <= ws_size) xh = (f16*)carve(SZ_XH);
    (void)in_sizes; (void)n_in; (void)out_size;

    hipMemsetAsync(bar, 0, SZ_BAR, stream);

    if (xh)  k_f32_to_f16<<<2048, 256, 0, stream>>>(x,  xh,  (T_ * B_ * I_) / 8);
    if (Wih) k_f32_to_f16<<<2048, 256, 0, stream>>>(Wi, Wih, (E_ * G4 * I_) / 8);
    k_f32_to_f16<<<2048, 256, 0, stream>>>(Wh, Whh, (E_ * G4 * H_) / 8);
    k_f32_to_f16<<<512,  256, 0, stream>>>(Wo, Woh, (E_ * C_ * H_) / 8);
    k_mix_biases<<<512, 256, 0, stream>>>(coef, bi, bh, bo, gbias, bom);
    k_init_h0h<<<(B_ * H_ + 255) / 256, 256, 0, stream>>>(h0, h0h);

    dim3 gx(32, 64);
    if (xh)
        k_xi_gemm<true,  true ><<<gx, 256, 0, stream>>>(xh, nullptr, Wih, nullptr, coef, gbias, xi);
    else if (Wih)
        k_xi_gemm<false, true ><<<gx, 256, 0, stream>>>(nullptr, x, Wih, nullptr, coef, gbias, xi);
    else
        k_xi_gemm<false, false><<<gx, 256, 0, stream>>>(nullptr, x, nullptr, Wi, coef, gbias, xi);

    // persistent recurrence: one cooperative launch, 256 blocks = 1/CU
    {
        void* args[] = { (void*)&Whh, (void*)&h0h, (void*)&c0, (void*)&xi,
                         (void*)&coef, (void*)&out, (void*)&bar };
        hipLaunchCooperativeKernel((const void*)k_rec_persist, dim3(256), dim3(256),
                                   args, 0, stream);
    }

    dim3 go(2, 256);
    k_out_gemm<<<go, 256, 0, stream>>>(xi, Woh, coef, bom, out);
}